// Round 16
// baseline (395.008 us; speedup 1.0000x reference)
//
#include <hip/hip_runtime.h>

// Bahdanau attention fused kernel for MI355X (gfx950).
// scores[b][s] = softmax_s( v . tanh( hb[b,:] + enc[s,b,:] @ We ) )
// R14: A-RESIDENT blocks. 32 rows x FULL N=1024 per block; A staged+converted
//      ONCE (no N-split redundancy), XOR-swizzled 64KB LDS; barrier-free main
//      loop; B-frags reg-loaded from L2-resident wt2 (fragment-contiguous
//      layout, 1KB/instr), 4-buffer ring, 2-step prefetch. 2 blocks/CU.

typedef _Float16 f16;
typedef _Float16 half8 __attribute__((ext_vector_type(8)));
typedef float f32x4 __attribute__((ext_vector_type(4)));

#define KDIM 1024
#define SEQ  2048

// ---------------------------------------------------------------------------
// prep_w: enc-half of attn_w -> fragment-contiguous f16 tiles.
// Entry t = (ks*64 + g)*64 + l  (ks 0..31, col-group g 0..63, lane l 0..63):
// wt2[t*8 + j] = W[1024 + ks*32 + (l>>4)*8 + j][g*16 + (l&15)]
// Main kernel: lane l's B-frag (ks, g) = 16B at wt2 + t*8 -> coalesced 1KB/wave.
// ---------------------------------------------------------------------------
__global__ __launch_bounds__(256) void prep_w(const float* __restrict__ w,
                                              f16* __restrict__ wt2) {
    int t  = blockIdx.x * 256 + threadIdx.x;   // 0..131071
    int l  = t & 63;
    int gk = t >> 6;
    int g  = gk & 63;
    int ks = gk >> 6;
    int kb = 1024 + ks * 32 + (l >> 4) * 8;
    int n  = g * 16 + (l & 15);
    half8 h;
#pragma unroll
    for (int j = 0; j < 8; ++j)
        h[j] = (f16)w[(size_t)(kb + j) * 1024 + n];
    *(half8*)&wt2[(size_t)t * 8] = h;
}

// ---------------------------------------------------------------------------
// prep_hb: hb[b][n] = attn_b[n] + sum_k hidden[b][k] * attn_w[k][n]  (f32)
// ---------------------------------------------------------------------------
__global__ __launch_bounds__(256) void prep_hb(const float* __restrict__ hidden,
                                               const float* __restrict__ attn_w,
                                               const float* __restrict__ attn_b,
                                               float* __restrict__ hb) {
    int b = blockIdx.x >> 2;
    int n = (blockIdx.x & 3) * 256 + threadIdx.x;
    const float* h = hidden + (size_t)b * 1024;
    float acc = attn_b[n];
#pragma unroll 8
    for (int k = 0; k < 1024; ++k)
        acc += h[k] * attn_w[(size_t)k * 1024 + n];
    hb[(size_t)b * 1024 + n] = acc;
}

// ---------------------------------------------------------------------------
// fused_energy: block = 32 flat rows x N=1024. 256 thr / 4 waves; wave wv owns
// col-groups {p*32 + wv*8 .. +7} per pass p. 64 steps (2 passes x 32 ks):
// 2 ds_read A-frags + 8 coalesced B loads (prefetch +2, ring b0..b3) + 16 MFMA.
// No barriers after the A-stage sync. Raw scores written to out.
// ---------------------------------------------------------------------------
__global__ __launch_bounds__(256, 2)
void fused_energy(const float* __restrict__ enc, const f16* __restrict__ wt2,
                  const float* __restrict__ hb, const float* __restrict__ vvec,
                  float* __restrict__ out) {
    __shared__ f16 Als[32 * 1024];   // 64 KB: row*2048B + (colB ^ ((row&7)<<4))
    __shared__ float red[4][32];

    const int tid  = threadIdx.x;
    const int lane = tid & 63;
    const int wv   = tid >> 6;       // 0..3
    const int l15  = lane & 15;
    const int l4   = lane >> 4;
    const int mrow0 = blockIdx.x * 32;

    // ---- stage A: 16 pairs/thread, loads first (bulk in flight), then cvt+write
    f32x4 s0[16], s1[16];
#pragma unroll
    for (int i = 0; i < 16; ++i) {
        int p = i * 256 + tid;                 // 0..4095
        int row = p >> 7, colp = p & 127;      // 128 x 32B pairs per row
        const float* src = enc + (size_t)(mrow0 + row) * KDIM + colp * 8;
        s0[i] = *(const f32x4*)src;
        s1[i] = *(const f32x4*)(src + 4);
    }
#pragma unroll
    for (int i = 0; i < 16; ++i) {
        int p = i * 256 + tid;
        int row = p >> 7, colp = p & 127;
        half8 h;
#pragma unroll
        for (int j = 0; j < 4; ++j) { h[j] = (f16)s0[i][j]; h[4 + j] = (f16)s1[i][j]; }
        int colB = (colp * 16) ^ ((row & 7) << 4);
        *(half8*)((char*)Als + row * 2048 + colB) = h;
    }

    // vv preload for both passes
    float vv[2][8];
#pragma unroll
    for (int p = 0; p < 2; ++p)
#pragma unroll
        for (int nj = 0; nj < 8; ++nj)
            vv[p][nj] = vvec[(p * 32 + wv * 8 + nj) * 16 + l15];

    // A-frag address components: r = mi*16 + l15
    int aRow[2], aSwz[2];
#pragma unroll
    for (int mi = 0; mi < 2; ++mi) {
        int r = mi * 16 + l15;
        aRow[mi] = r * 2048;
        aSwz[mi] = (r & 7) << 4;
    }
    const int aK = l4 * 16;

    half8 b0[8], b1[8], b2[8], b3[8];

#define LOADB(S, R)                                                           \
    _Pragma("unroll") for (int nj = 0; nj < 8; ++nj)                          \
        R[nj] = *(const half8*)(wt2 +                                         \
            ((size_t)((((S) & 31) * 64 + ((S) >> 5) * 32 + wv * 8 + nj)) * 64 \
             + lane) * 8);

    LOADB(0, b0);
    LOADB(1, b1);
    __syncthreads();                 // Als ready (one-time full drain)

    const f32x4 zero = {0.f, 0.f, 0.f, 0.f};
    f32x4 acc[2][8];
#pragma unroll
    for (int mi = 0; mi < 2; ++mi)
#pragma unroll
        for (int nj = 0; nj < 8; ++nj) acc[mi][nj] = zero;

    float part[2][4];
#pragma unroll
    for (int mi = 0; mi < 2; ++mi)
#pragma unroll
        for (int rg = 0; rg < 4; ++rg) part[mi][rg] = 0.f;

#define STEP(S, BC, BN)                                                       \
    {                                                                         \
        LOADB((S) + 2, BN);                                                   \
        half8 af0 = *(const half8*)((char*)Als + aRow[0] +                    \
                                    ((((S) & 31) * 64 + aK) ^ aSwz[0]));      \
        half8 af1 = *(const half8*)((char*)Als + aRow[1] +                    \
                                    ((((S) & 31) * 64 + aK) ^ aSwz[1]));      \
        __builtin_amdgcn_s_setprio(1);                                        \
        _Pragma("unroll") for (int nj = 0; nj < 8; ++nj) {                    \
            acc[0][nj] = __builtin_amdgcn_mfma_f32_16x16x32_f16(              \
                af0, BC[nj], acc[0][nj], 0, 0, 0);                            \
            acc[1][nj] = __builtin_amdgcn_mfma_f32_16x16x32_f16(              \
                af1, BC[nj], acc[1][nj], 0, 0, 0);                            \
        }                                                                     \
        __builtin_amdgcn_s_setprio(0);                                        \
    }
#define STEPN(S, BC)                                                          \
    {                                                                         \
        half8 af0 = *(const half8*)((char*)Als + aRow[0] +                    \
                                    ((((S) & 31) * 64 + aK) ^ aSwz[0]));      \
        half8 af1 = *(const half8*)((char*)Als + aRow[1] +                    \
                                    ((((S) & 31) * 64 + aK) ^ aSwz[1]));      \
        __builtin_amdgcn_s_setprio(1);                                        \
        _Pragma("unroll") for (int nj = 0; nj < 8; ++nj) {                    \
            acc[0][nj] = __builtin_amdgcn_mfma_f32_16x16x32_f16(              \
                af0, BC[nj], acc[0][nj], 0, 0, 0);                            \
            acc[1][nj] = __builtin_amdgcn_mfma_f32_16x16x32_f16(              \
                af1, BC[nj], acc[1][nj], 0, 0, 0);                            \
        }                                                                     \
        __builtin_amdgcn_s_setprio(0);                                        \
    }
#define EPI(P)                                                                \
    _Pragma("unroll") for (int mi = 0; mi < 2; ++mi)                          \
    _Pragma("unroll") for (int rg = 0; rg < 4; ++rg) {                        \
        int row = mi * 16 + l4 * 4 + rg;                                      \
        const float* hbr = hb + (size_t)((mrow0 + row) & 31) * 1024           \
                           + ((P) * 32 + wv * 8) * 16 + l15;                  \
        float sum = 0.f;                                                      \
        _Pragma("unroll") for (int nj = 0; nj < 8; ++nj) {                    \
            float e  = acc[mi][nj][rg] + hbr[nj * 16];                        \
            float e2 = __expf(2.f * e);                                       \
            sum += (1.f - 2.f / (e2 + 1.f)) * vv[P][nj];                      \
        }                                                                     \
        part[mi][rg] += sum;                                                  \
    }

    // ---- pass 0: steps 0..31 (prefetch crosses into pass 1) ----
    for (int s = 0; s < 32; s += 4) {
        STEP(s,     b0, b2);
        STEP(s + 1, b1, b3);
        STEP(s + 2, b2, b0);
        STEP(s + 3, b3, b1);
    }
    EPI(0);
#pragma unroll
    for (int mi = 0; mi < 2; ++mi)
#pragma unroll
        for (int nj = 0; nj < 8; ++nj) acc[mi][nj] = zero;

    // ---- pass 1: steps 32..59, then tail 60..63 ----
    for (int s = 32; s < 60; s += 4) {
        STEP(s,     b0, b2);
        STEP(s + 1, b1, b3);
        STEP(s + 2, b2, b0);
        STEP(s + 3, b3, b1);
    }
    STEP(60, b0, b2);    // loads 62
    STEP(61, b1, b3);    // loads 63
    STEPN(62, b2);
    STEPN(63, b3);
    EPI(1);

#undef LOADB
#undef STEP
#undef STEPN
#undef EPI

    // ---- final reduce: sum 16 col-lanes, then 4 waves ----
#pragma unroll
    for (int mi = 0; mi < 2; ++mi) {
#pragma unroll
        for (int rg = 0; rg < 4; ++rg) {
            float p = part[mi][rg];
            p += __shfl_xor(p, 1);
            p += __shfl_xor(p, 2);
            p += __shfl_xor(p, 4);
            p += __shfl_xor(p, 8);
            if (l15 == 0) red[wv][mi * 16 + l4 * 4 + rg] = p;
        }
    }
    __syncthreads();
    if (tid < 32) {
        float s = red[0][tid] + red[1][tid] + red[2][tid] + red[3][tid];
        int rG = mrow0 + tid;                   // flat row = s*32 + b
        out[(size_t)(rG & 31) * SEQ + (rG >> 5)] = s;
    }
}

// ---------------------------------------------------------------------------
// softmax over S=2048 per batch row, in-place on out
// ---------------------------------------------------------------------------
__global__ __launch_bounds__(256) void softmax_rows(float* __restrict__ out) {
    const int b = blockIdx.x;
    float* row = out + (size_t)b * SEQ;
    const int tid  = threadIdx.x;
    const int lane = tid & 63;
    const int wv   = tid >> 6;
    __shared__ float sred[4];
    __shared__ float ssum[4];
    float x[8];
    float mx = -3.4e38f;
#pragma unroll
    for (int j = 0; j < 8; ++j) { x[j] = row[tid + j * 256]; mx = fmaxf(mx, x[j]); }
#pragma unroll
    for (int o = 1; o < 64; o <<= 1) mx = fmaxf(mx, __shfl_xor(mx, o));
    if (lane == 0) sred[wv] = mx;
    __syncthreads();
    mx = fmaxf(fmaxf(sred[0], sred[1]), fmaxf(sred[2], sred[3]));
    float s = 0.f;
#pragma unroll
    for (int j = 0; j < 8; ++j) { x[j] = __expf(x[j] - mx); s += x[j]; }
#pragma unroll
    for (int o = 1; o < 64; o <<= 1) s += __shfl_xor(s, o);
    if (lane == 0) ssum[wv] = s;
    __syncthreads();
    s = ssum[0] + ssum[1] + ssum[2] + ssum[3];
    float inv = 1.f / s;
#pragma unroll
    for (int j = 0; j < 8; ++j) row[tid + j * 256] = x[j] * inv;
}

extern "C" void kernel_launch(void* const* d_in, const int* in_sizes, int n_in,
                              void* d_out, int out_size, void* d_ws, size_t ws_size,
                              hipStream_t stream) {
    const float* hidden = (const float*)d_in[0];   // [32][1024]
    const float* enc    = (const float*)d_in[1];   // [2048][32][1024]
    const float* attn_w = (const float*)d_in[2];   // [2048][1024]
    const float* attn_b = (const float*)d_in[3];   // [1024]
    const float* v      = (const float*)d_in[4];   // [1024]
    float* out = (float*)d_out;                    // [32][2048]

    f16*   wt2 = (f16*)d_ws;                       // 2 MB fragment-tiled We
    float* hb  = (float*)((char*)d_ws + 2097152);  // 128 KB

    prep_w<<<512, 256, 0, stream>>>(attn_w, wt2);
    prep_hb<<<128, 256, 0, stream>>>(hidden, attn_w, attn_b, hb);
    fused_energy<<<2048, 256, 0, stream>>>(enc, wt2, hb, v, out);
    softmax_rows<<<32, 256, 0, stream>>>(out);
}

// Round 17
// 316.978 us; speedup vs baseline: 1.2462x; 1.2462x over previous
//
#include <hip/hip_runtime.h>

// Bahdanau attention fused kernel for MI355X (gfx950).
// scores[b][s] = softmax_s( v . tanh( hb[b,:] + enc[s,b,:] @ We ) )
// R15: m97-verbatim loop. BOTH operands staged via global_load_lds (A as raw
//      f32 with pre-swizzled global source, rule #21; convert at frag-read),
//      double-buffered, ONE __syncthreads per K-step, compiler waits,
//      3 blocks/CU. 128x128 tile, nq=8 N-slices, XCD-grouped.

typedef _Float16 f16;
typedef _Float16 half8 __attribute__((ext_vector_type(8)));
typedef float f32x4 __attribute__((ext_vector_type(4)));

#define KDIM 1024
#define SEQ  2048
#define MROWS 65536

typedef __attribute__((address_space(1))) void gvoid;
typedef __attribute__((address_space(3))) void svoid;

__device__ __forceinline__ void gload_lds16(const void* g, void* l) {
    __builtin_amdgcn_global_load_lds((const gvoid*)g, (svoid*)l, 16, 0, 0);
}

// ---------------------------------------------------------------------------
// prep_w: transpose + f16-convert enc-half of attn_w into [128 n][32 k] tile
// images (8KB each), tile tk = nq*32 + ks; 16B block
// p = nloc*4 + ((kblk + (nloc>>1)) & 3)  [R12 layout, measured 0 conflicts].
// ---------------------------------------------------------------------------
__global__ __launch_bounds__(256) void prep_w(const float* __restrict__ w,
                                              f16* __restrict__ wt) {
    int idx  = blockIdx.x * 256 + threadIdx.x;   // 0..131071
    int kblk = idx & 3;
    int nloc = (idx >> 2) & 127;
    int tk   = idx >> 9;                         // 0..255
    int ks   = tk & 31, nq = tk >> 5;
    int n_g  = nq * 128 + nloc;
    int kb   = 1024 + ks * 32 + kblk * 8;
    half8 h;
#pragma unroll
    for (int j = 0; j < 8; ++j)
        h[j] = (f16)w[(size_t)(kb + j) * 1024 + n_g];
    int p = nloc * 4 + ((kblk + (nloc >> 1)) & 3);
    *(half8*)&wt[(size_t)tk * 4096 + p * 8] = h;
}

// ---------------------------------------------------------------------------
// prep_hb: hb[b][n] = attn_b[n] + sum_k hidden[b][k] * attn_w[k][n]  (f32)
// ---------------------------------------------------------------------------
__global__ __launch_bounds__(256) void prep_hb(const float* __restrict__ hidden,
                                               const float* __restrict__ attn_w,
                                               const float* __restrict__ attn_b,
                                               float* __restrict__ hb) {
    int b = blockIdx.x >> 2;
    int n = (blockIdx.x & 3) * 256 + threadIdx.x;
    const float* h = hidden + (size_t)b * 1024;
    float acc = attn_b[n];
#pragma unroll 8
    for (int k = 0; k < 1024; ++k)
        acc += h[k] * attn_w[(size_t)k * 1024 + n];
    hb[(size_t)b * 1024 + n] = acc;
}

// ---------------------------------------------------------------------------
// fused_energy: block = 128 rows x 128 N-slice (nq of 8); K = 32 steps of 32.
// 4 waves (2M x 2N), wave tile 64x64, frags 4(M) x 4(N), 16 MFMA/step/wave.
// A staged as f32 via global_load_lds with granule-swizzled global source:
//   LDS slot s (16B): r=s>>3, h=s&7, pos=h>>1, half=h&1
//   source granule g = pos ^ (r&3), srcHalf = half ^ ((r>>2)&1)
// Frag read (lane l15,l4; row r): lo@ r*128+(l4^(r&3))*32+((r>>2)&1)*16,
// hi@ same +-16. 2 lanes/bank (free). Convert f32->f16 at frag assembly.
// ---------------------------------------------------------------------------
__global__ __launch_bounds__(256, 3)
void fused_energy(const float* __restrict__ enc, const f16* __restrict__ wt,
                  const float* __restrict__ hb, const float* __restrict__ vvec,
                  float* __restrict__ partout) {
    __shared__ char AlsA[2][16384];   // 2 x 16KB A f32 double buffer
    __shared__ char AlsB[2][8192];    // 2 x 8KB  B f16 double buffer
    __shared__ float red[2][128];

    const int tid  = threadIdx.x;
    const int lane = tid & 63;
    const int wv   = tid >> 6;          // 0..3
    const int wm   = wv >> 1;           // 0..1: 64-row group
    const int wn   = wv & 1;            // 0..1: 64-col group
    const int l15  = lane & 15;
    const int l4   = lane >> 4;

    // XCD mapping: all 8 nq-slices of a row-tile consecutive on one XCD
    const int bid   = blockIdx.x;       // 0..4095
    const int xcd   = bid & 7;
    const int chunk = bid >> 3;         // 0..511
    const int mt    = xcd * 64 + (chunk >> 3);   // 0..511
    const int nq    = chunk & 7;                 // 0..7
    const int mrow0 = mt * 128;
    const int ncol0 = nq * 128;

    const char* wtNq = (const char*)wt + (size_t)nq * 32 * 8192;

    // A stage source pointers (pre-swizzled global addresses, rule #21):
    // instruction i stages LDS slots s = i*256 + tid.
    const float* aSrc[4];
    int aDst[4];
#pragma unroll
    for (int i = 0; i < 4; ++i) {
        int s    = i * 256 + tid;
        int r    = s >> 3;
        int h    = s & 7;
        int pos  = h >> 1;
        int half = h & 1;
        int g    = pos ^ (r & 3);
        int sh   = half ^ ((r >> 2) & 1);
        aSrc[i] = enc + (size_t)(mrow0 + r) * KDIM + g * 8 + sh * 4;
        aDst[i] = s * 16;
    }

    // A frag read offsets (within buffer): r = wm*64 + mi*16 + l15
    int aLo[4], aHi[4];
#pragma unroll
    for (int mi = 0; mi < 4; ++mi) {
        int r   = wm * 64 + mi * 16 + l15;
        int bse = r * 128 + ((l4 ^ (r & 3)) * 32);
        int hb_ = (r >> 2) & 1;
        aLo[mi] = bse + hb_ * 16;
        aHi[mi] = bse + (1 - hb_) * 16;
    }
    int bOffB[4];
#pragma unroll
    for (int nj = 0; nj < 4; ++nj) {
        int n = wn * 64 + nj * 16 + l15;
        bOffB[nj] = (n * 4 + ((l4 + (n >> 1)) & 3)) * 16;
    }

    const f32x4 zero = {0.f, 0.f, 0.f, 0.f};
    f32x4 acc[4][4];
#pragma unroll
    for (int mi = 0; mi < 4; ++mi)
#pragma unroll
        for (int nj = 0; nj < 4; ++nj) acc[mi][nj] = zero;

#define STAGE(KS, BUF)                                                        \
    {                                                                         \
        char* da_ = AlsA[BUF];                                                \
        _Pragma("unroll") for (int i = 0; i < 4; ++i)                         \
            gload_lds16(aSrc[i] + (KS) * 32, da_ + aDst[i]);                  \
        const char* sb_ = wtNq + (size_t)(KS) * 8192 + tid * 16;              \
        char* db_ = AlsB[BUF] + tid * 16;                                     \
        gload_lds16(sb_, db_);                                                \
        gload_lds16(sb_ + 4096, db_ + 4096);                                  \
    }
#define COMPUTE(BUF)                                                          \
    {                                                                         \
        const char* ab_ = AlsA[BUF];                                          \
        const char* bb_ = AlsB[BUF];                                          \
        f32x4 alo[4], ahi[4];                                                 \
        half8 bf[4], af[4];                                                   \
        _Pragma("unroll") for (int mi = 0; mi < 4; ++mi) {                    \
            alo[mi] = *(const f32x4*)(ab_ + aLo[mi]);                         \
            ahi[mi] = *(const f32x4*)(ab_ + aHi[mi]);                         \
        }                                                                     \
        _Pragma("unroll") for (int nj = 0; nj < 4; ++nj)                      \
            bf[nj] = *(const half8*)(bb_ + bOffB[nj]);                        \
        _Pragma("unroll") for (int mi = 0; mi < 4; ++mi)                      \
            _Pragma("unroll") for (int j = 0; j < 4; ++j) {                   \
                af[mi][j]     = (f16)alo[mi][j];                              \
                af[mi][4 + j] = (f16)ahi[mi][j];                              \
            }                                                                 \
        __builtin_amdgcn_s_setprio(1);                                        \
        _Pragma("unroll") for (int mi = 0; mi < 4; ++mi)                      \
            _Pragma("unroll") for (int nj = 0; nj < 4; ++nj)                  \
                acc[mi][nj] = __builtin_amdgcn_mfma_f32_16x16x32_f16(         \
                    af[mi], bf[nj], acc[mi][nj], 0, 0, 0);                    \
        __builtin_amdgcn_s_setprio(0);                                        \
    }

    // ---- prologue ----
    STAGE(0, 0);
    __syncthreads();

    // ---- main loop: stage(ks+1) | compute(ks) | barrier ----
#pragma unroll 2
    for (int ks = 0; ks < 31; ++ks) {
        STAGE(ks + 1, (ks & 1) ^ 1);
        COMPUTE(ks & 1);
        __syncthreads();
    }
    COMPUTE(1);

#undef STAGE
#undef COMPUTE

    // ---- epilogue: e = acc + hb -> tanh -> * v -> per-row partial ----
    float vv[4];
#pragma unroll
    for (int nj = 0; nj < 4; ++nj)
        vv[nj] = vvec[ncol0 + wn * 64 + nj * 16 + l15];
#pragma unroll
    for (int mi = 0; mi < 4; ++mi) {
#pragma unroll
        for (int rg = 0; rg < 4; ++rg) {
            int rl = wm * 64 + mi * 16 + l4 * 4 + rg;     // local row 0..127
            const float* hbrow = hb + (size_t)((mrow0 + rl) & 31) * 1024
                                 + ncol0 + wn * 64 + l15;
            float sum = 0.f;
#pragma unroll
            for (int nj = 0; nj < 4; ++nj) {
                float e  = acc[mi][nj][rg] + hbrow[nj * 16];
                float e2 = __expf(2.f * e);
                sum += (1.f - 2.f / (e2 + 1.f)) * vv[nj];  // tanh(e) * v
            }
            float p = sum;
            p += __shfl_xor(p, 1);
            p += __shfl_xor(p, 2);
            p += __shfl_xor(p, 4);
            p += __shfl_xor(p, 8);
            if (l15 == 0) red[wn][rl] = p;
        }
    }
    __syncthreads();
    if (tid < 128) {
        float s = red[0][tid] + red[1][tid];
        partout[(size_t)nq * MROWS + mrow0 + tid] = s;
    }
}

// ---------------------------------------------------------------------------
// softmax over S=2048 per batch row; sums the 8 N-slice partials first.
// ---------------------------------------------------------------------------
__global__ __launch_bounds__(256) void softmax_rows(const float* __restrict__ part,
                                                    float* __restrict__ out) {
    const int b = blockIdx.x;
    const int tid  = threadIdx.x;
    const int lane = tid & 63;
    const int wv   = tid >> 6;
    __shared__ float sred[4];
    __shared__ float ssum[4];
    float x[8];
    float mx = -3.4e38f;
#pragma unroll
    for (int j = 0; j < 8; ++j) {
        int flat = (tid + j * 256) * 32 + b;              // row = s*32 + b
        float v = 0.f;
#pragma unroll
        for (int q = 0; q < 8; ++q) v += part[(size_t)q * MROWS + flat];
        x[j] = v;
        mx = fmaxf(mx, v);
    }
#pragma unroll
    for (int o = 1; o < 64; o <<= 1) mx = fmaxf(mx, __shfl_xor(mx, o));
    if (lane == 0) sred[wv] = mx;
    __syncthreads();
    mx = fmaxf(fmaxf(sred[0], sred[1]), fmaxf(sred[2], sred[3]));
    float s = 0.f;
#pragma unroll
    for (int j = 0; j < 8; ++j) { x[j] = __expf(x[j] - mx); s += x[j]; }
#pragma unroll
    for (int o = 1; o < 64; o <<= 1) s += __shfl_xor(s, o);
    if (lane == 0) ssum[wv] = s;
    __syncthreads();
    s = ssum[0] + ssum[1] + ssum[2] + ssum[3];
    float inv = 1.f / s;
#pragma unroll
    for (int j = 0; j < 8; ++j) out[(size_t)b * SEQ + tid + j * 256] = x[j] * inv;
}

extern "C" void kernel_launch(void* const* d_in, const int* in_sizes, int n_in,
                              void* d_out, int out_size, void* d_ws, size_t ws_size,
                              hipStream_t stream) {
    const float* hidden = (const float*)d_in[0];   // [32][1024]
    const float* enc    = (const float*)d_in[1];   // [2048][32][1024]
    const float* attn_w = (const float*)d_in[2];   // [2048][1024]
    const float* attn_b = (const float*)d_in[3];   // [1024]
    const float* v      = (const float*)d_in[4];   // [1024]
    float* out = (float*)d_out;                    // [32][2048]

    f16*   wt   = (f16*)d_ws;                              // 2 MB tiled We
    float* hb   = (float*)((char*)d_ws + 2097152);         // 128 KB
    float* part = (float*)((char*)d_ws + 2097152 + 131072); // 2 MB (8 slices)

    prep_w<<<512, 256, 0, stream>>>(attn_w, wt);
    prep_hb<<<128, 256, 0, stream>>>(hidden, attn_w, attn_b, hb);
    fused_energy<<<4096, 256, 0, stream>>>(enc, wt, hb, v, part);
    softmax_rows<<<32, 256, 0, stream>>>(part, out);
}

// Round 18
// 279.424 us; speedup vs baseline: 1.4137x; 1.1344x over previous
//
#include <hip/hip_runtime.h>

// Bahdanau attention fused kernel for MI355X (gfx950).
// scores[b][s] = softmax_s( v . tanh( hb[b,:] + enc[s,b,:] @ We ) )
// R18: faithful counted-window schedule (T3/T4). 256x256 tile, 8 waves 2Mx4N,
//      K-half steps of 32; 4-slot LDS rings (A 64KB + B 64KB); per step:
//      2 phases x 16 MFMA; vmcnt(8) windows >=2 steps; cvt off critical path;
//      reads issued pre-barrier; never vmcnt(0) mid-loop. 1 block/CU.

typedef _Float16 f16;
typedef _Float16 half4 __attribute__((ext_vector_type(4)));
typedef _Float16 half8 __attribute__((ext_vector_type(8)));
typedef float f32x4 __attribute__((ext_vector_type(4)));

#define KDIM 1024
#define SEQ  2048
#define MROWS 65536

typedef __attribute__((address_space(1))) void gvoid;
typedef __attribute__((address_space(3))) void svoid;

__device__ __forceinline__ void gload_lds16(const void* g, void* l) {
    __builtin_amdgcn_global_load_lds((const gvoid*)g, (svoid*)l, 16, 0, 0);
}

// ---------------------------------------------------------------------------
// prep_w: transpose + f16-convert enc-half of attn_w into [256 n][32 k] tile
// images (16KB each), tile tk = nq*32 + u (khalf u); 16B block
// p = nloc*4 + ((kblk + (nloc>>1)) & 3)   [validated R6-R8].
// ---------------------------------------------------------------------------
__global__ __launch_bounds__(256) void prep_w(const float* __restrict__ w,
                                              f16* __restrict__ wt) {
    int idx  = blockIdx.x * 256 + threadIdx.x;   // 0..131071
    int kblk = idx & 3;
    int nloc = (idx >> 2) & 255;
    int tk   = idx >> 10;                        // 0..127
    int u    = tk & 31, nq = tk >> 5;
    int n_g  = nq * 256 + nloc;
    int kb   = 1024 + u * 32 + kblk * 8;
    half8 h;
#pragma unroll
    for (int j = 0; j < 8; ++j)
        h[j] = (f16)w[(size_t)(kb + j) * 1024 + n_g];
    int p = nloc * 4 + ((kblk + (nloc >> 1)) & 3);
    *(half8*)&wt[(size_t)tk * 8192 + p * 8] = h;
}

// ---------------------------------------------------------------------------
// prep_hb: hb[b][n] = attn_b[n] + sum_k hidden[b][k] * attn_w[k][n]  (f32)
// ---------------------------------------------------------------------------
__global__ __launch_bounds__(256) void prep_hb(const float* __restrict__ hidden,
                                               const float* __restrict__ attn_w,
                                               const float* __restrict__ attn_b,
                                               float* __restrict__ hb) {
    int b = blockIdx.x >> 2;
    int n = (blockIdx.x & 3) * 256 + threadIdx.x;
    const float* h = hidden + (size_t)b * 1024;
    float acc = attn_b[n];
#pragma unroll 8
    for (int k = 0; k < 1024; ++k)
        acc += h[k] * attn_w[(size_t)k * 1024 + n];
    hb[(size_t)b * 1024 + n] = acc;
}

// ---------------------------------------------------------------------------
// fused_energy: block = 256 rows x 256 N-slice (nq of 4); K = 32 khalf steps.
// 8 waves (2M x 4N), wave tile 128x64, frags 8(M) x 4(N), 32 MFMA/step/wave.
// A: coalesced f32 loads (8x128B segs/instr) -> cvt -> XOR-swizzled ds_write,
//    one step ahead of use. B: gload_lds from pre-swizzled tile images.
// Steady FIFO entering step u: [B(u+1):2, A(u+2):4, B(u+2):2] = 8.
// ---------------------------------------------------------------------------
__global__ __launch_bounds__(512, 2)
void fused_energy(const float* __restrict__ enc, const f16* __restrict__ wt,
                  const float* __restrict__ hb, const float* __restrict__ vvec,
                  float* __restrict__ partout) {
    __shared__ char AL[4 * 16384];   // A ring: slot = [256 rows][64B swizzled]
    __shared__ char BL[4 * 16384];   // B ring: slot = [256 n][32 k] image
    __shared__ float red[4][256];

    const int tid  = threadIdx.x;
    const int lane = tid & 63;
    const int wv   = tid >> 6;          // 0..7
    const int wm   = wv >> 2;           // 0..1: 128-row group
    const int wn   = wv & 3;            // 0..3: 64-col group
    const int l15  = lane & 15;
    const int l4   = lane >> 4;

    // XCD mapping: 4 nq-slices of one row-tile consecutive on one XCD
    const int bid   = blockIdx.x;       // 0..1023
    const int xcd   = bid & 7;
    const int c     = bid >> 3;         // 0..127
    const int mt    = xcd * 32 + (c >> 2);       // 0..255
    const int nq    = c & 3;
    const int mrow0 = mt * 256;
    const int ncol0 = nq * 256;

    const char* wtNq = (const char*)wt + (size_t)nq * 32 * 16384;

    // A staging: thread t -> rows {arow + i*64}, granule ag (16B f32 = 4 k)
    const int arow = tid >> 3;          // 0..63
    const int ag   = tid & 7;
    const float* aSrc = enc + (size_t)(mrow0 + arow) * KDIM + ag * 4;
    const int aw0 = arow * 64 + (((ag >> 1) * 16) ^ ((arow & 3) << 4)) + (ag & 1) * 8;

    // fragment offsets
    int aOff[8], bOff[4];
#pragma unroll
    for (int mi = 0; mi < 8; ++mi) {
        int r = wm * 128 + mi * 16 + l15;
        aOff[mi] = r * 64 + ((l4 * 16) ^ ((r & 3) << 4));
    }
#pragma unroll
    for (int nj = 0; nj < 4; ++nj) {
        int n = wn * 64 + nj * 16 + l15;
        bOff[nj] = (n * 4 + ((l4 + (n >> 1)) & 3)) * 16;
    }

    const f32x4 zero = {0.f, 0.f, 0.f, 0.f};
    f32x4 acc[8][4];
#pragma unroll
    for (int mi = 0; mi < 8; ++mi)
#pragma unroll
        for (int nj = 0; nj < 4; ++nj) acc[mi][nj] = zero;

    f32x4 rEv[4], rOd[4];
    half8 af[4], bf[4];

#define WAITV(N) asm volatile("s_waitcnt vmcnt(" #N ")" ::: "memory")
#define LGKM0    asm volatile("s_waitcnt lgkmcnt(0)" ::: "memory")
#define SCB0     __builtin_amdgcn_sched_barrier(0)
#define BAR      __builtin_amdgcn_s_barrier()
#define PRIO1    __builtin_amdgcn_s_setprio(1)
#define PRIO0    __builtin_amdgcn_s_setprio(0)

#define LOADA(W, R)                                                           \
    { _Pragma("unroll") for (int i = 0; i < 4; ++i)                           \
        R[i] = *(const f32x4*)(aSrc + (size_t)(i * 64) * KDIM + (W) * 32); }
#define STAGEB(W)                                                             \
    { const char* s_ = wtNq + (size_t)(W) * 16384 + tid * 16;                 \
      char* d_ = BL + ((W) & 3) * 16384 + tid * 16;                           \
      gload_lds16(s_, d_);                                                    \
      gload_lds16(s_ + 8192, d_ + 8192); }
#define CVWR(W, R)                                                            \
    { char* b_ = AL + ((W) & 3) * 16384;                                      \
      _Pragma("unroll") for (int i = 0; i < 4; ++i) {                         \
          half4 h_;                                                           \
          _Pragma("unroll") for (int j = 0; j < 4; ++j) h_[j] = (f16)R[i][j]; \
          *(half4*)(b_ + aw0 + i * 4096) = h_;                                \
      } }
#define READB(U)                                                              \
    { const char* s_ = BL + ((U) & 3) * 16384;                                \
      _Pragma("unroll") for (int nj = 0; nj < 4; ++nj)                        \
          bf[nj] = *(const half8*)(s_ + bOff[nj]); }
#define READA(U, MH)                                                          \
    { const char* s_ = AL + ((U) & 3) * 16384;                                \
      _Pragma("unroll") for (int j = 0; j < 4; ++j)                           \
          af[j] = *(const half8*)(s_ + aOff[(MH) * 4 + j]); }
#define MFMA16(MH)                                                            \
    PRIO1;                                                                    \
    _Pragma("unroll") for (int j = 0; j < 4; ++j)                             \
        _Pragma("unroll") for (int nj = 0; nj < 4; ++nj)                      \
            acc[(MH) * 4 + j][nj] = __builtin_amdgcn_mfma_f32_16x16x32_f16(   \
                af[j], bf[nj], acc[(MH) * 4 + j][nj], 0, 0, 0);               \
    PRIO0;

// Steady step u: Ph0 issues {A(u+3), B(u+3)}, computes quadrant 0 of slot u,
// then vmcnt(8) retires {B(u+1), A(u+2)} (both >=2 steps old), cvt+write
// A(u+2). Ph1 computes quadrant 1. Barriers carry no vmcnt drains.
#define STEP(U, RC, RI, DOISS, WMODE)                                         \
    {                                                                         \
        if (DOISS) { LOADA((U) + 3, RI); STAGEB((U) + 3); }                   \
        READB(U); READA(U, 0);                                                \
        MFMA16(0);                                                            \
        if ((WMODE) == 0) { WAITV(8); CVWR((U) + 2, RC); }                    \
        else if ((WMODE) == 1) { WAITV(2); CVWR((U) + 2, RC); }               \
        else if ((WMODE) == 2) { WAITV(0); }                                  \
        BAR;                                                                  \
        READA(U, 1);                                                          \
        MFMA16(1);                                                            \
        LGKM0; SCB0;                                                          \
        BAR;                                                                  \
    }

    // ---- prologue: A0,A1 staged+written; A2,B2 in flight ----
    LOADA(0, rEv); STAGEB(0);
    LOADA(1, rOd); STAGEB(1);            // out: 12
    WAITV(8);                            // retire A0
    CVWR(0, rEv);
    LOADA(2, rEv); STAGEB(2);            // out: 14
    WAITV(6);                            // retire B0, A1 (B1 early, harmless)
    CVWR(1, rOd);
    LGKM0; SCB0;
    BAR;

    // ---- steady: u = 0..27 (paired for A-reg parity), 28; tail 29..31 ----
    for (int u = 0; u < 28; u += 2) {
        STEP(u,     rEv, rOd, 1, 0);     // cvt A(u+2)<-rEv, issue A(u+3)->rOd
        STEP(u + 1, rOd, rEv, 1, 0);
    }
    STEP(28, rEv, rOd, 1, 0);            // issues A31->rOd, cvt A30<-rEv
    STEP(29, rOd, rEv, 0, 1);            // vmcnt(2), cvt A31<-rOd
    STEP(30, rEv, rOd, 0, 2);            // vmcnt(0) (drain B31)
    STEP(31, rOd, rEv, 0, 3);            // pure compute

#undef LOADA
#undef STAGEB
#undef CVWR
#undef READB
#undef READA
#undef MFMA16
#undef STEP

    // ---- epilogue: e = acc + hb -> tanh -> * v -> per-row partial ----
    float vv[4];
#pragma unroll
    for (int nj = 0; nj < 4; ++nj)
        vv[nj] = vvec[ncol0 + wn * 64 + nj * 16 + l15];
#pragma unroll
    for (int mi = 0; mi < 8; ++mi) {
#pragma unroll
        for (int rg = 0; rg < 4; ++rg) {
            int rl = wm * 128 + mi * 16 + l4 * 4 + rg;    // local row 0..255
            const float* hbrow = hb + (size_t)((mrow0 + rl) & 31) * 1024
                                 + ncol0 + wn * 64 + l15;
            float sum = 0.f;
#pragma unroll
            for (int nj = 0; nj < 4; ++nj) {
                float e  = acc[mi][nj][rg] + hbrow[nj * 16];
                float e2 = __expf(2.f * e);
                sum += (1.f - 2.f / (e2 + 1.f)) * vv[nj];  // tanh(e) * v
            }
            float p = sum;
            p += __shfl_xor(p, 1);
            p += __shfl_xor(p, 2);
            p += __shfl_xor(p, 4);
            p += __shfl_xor(p, 8);
            if (l15 == 0) red[wn][rl] = p;
        }
    }
    __syncthreads();
    if (tid < 256) {
        float s = red[0][tid] + red[1][tid] + red[2][tid] + red[3][tid];
        partout[(size_t)nq * MROWS + mrow0 + tid] = s;
    }
}

// ---------------------------------------------------------------------------
// softmax over S=2048 per batch row; sums the 4 N-slice partials first.
// ---------------------------------------------------------------------------
__global__ __launch_bounds__(256) void softmax_rows(const float* __restrict__ part,
                                                    float* __restrict__ out) {
    const int b = blockIdx.x;
    const int tid  = threadIdx.x;
    const int lane = tid & 63;
    const int wv   = tid >> 6;
    __shared__ float sred[4];
    __shared__ float ssum[4];
    float x[8];
    float mx = -3.4e38f;
#pragma unroll
    for (int j = 0; j < 8; ++j) {
        int flat = (tid + j * 256) * 32 + b;              // row = s*32 + b
        float v = part[flat] + part[MROWS + flat]
                + part[2 * MROWS + flat] + part[3 * MROWS + flat];
        x[j] = v;
        mx = fmaxf(mx, v);
    }
#pragma unroll
    for (int o = 1; o < 64; o <<= 1) mx = fmaxf(mx, __shfl_xor(mx, o));
    if (lane == 0) sred[wv] = mx;
    __syncthreads();
    mx = fmaxf(fmaxf(sred[0], sred[1]), fmaxf(sred[2], sred[3]));
    float s = 0.f;
#pragma unroll
    for (int j = 0; j < 8; ++j) { x[j] = __expf(x[j] - mx); s += x[j]; }
#pragma unroll
    for (int o = 1; o < 64; o <<= 1) s += __shfl_xor(s, o);
    if (lane == 0) ssum[wv] = s;
    __syncthreads();
    s = ssum[0] + ssum[1] + ssum[2] + ssum[3];
    float inv = 1.f / s;
#pragma unroll
    for (int j = 0; j < 8; ++j) out[(size_t)b * SEQ + tid + j * 256] = x[j] * inv;
}

extern "C" void kernel_launch(void* const* d_in, const int* in_sizes, int n_in,
                              void* d_out, int out_size, void* d_ws, size_t ws_size,
                              hipStream_t stream) {
    const float* hidden = (const float*)d_in[0];   // [32][1024]
    const float* enc    = (const float*)d_in[1];   // [2048][32][1024]
    const float* attn_w = (const float*)d_in[2];   // [2048][1024]
    const float* attn_b = (const float*)d_in[3];   // [1024]
    const float* v      = (const float*)d_in[4];   // [1024]
    float* out = (float*)d_out;                    // [32][2048]

    f16*   wt   = (f16*)d_ws;                              // 2 MB tiled We
    float* hb   = (float*)((char*)d_ws + 2097152);         // 128 KB
    float* part = (float*)((char*)d_ws + 2097152 + 131072); // 1 MB (4 slices)

    prep_w<<<512, 256, 0, stream>>>(attn_w, wt);
    prep_hb<<<128, 256, 0, stream>>>(hidden, attn_w, attn_b, hb);
    fused_energy<<<1024, 512, 0, stream>>>(enc, wt, hb, v, part);
    softmax_rows<<<32, 256, 0, stream>>>(part, out);
}

// Round 19
// 273.618 us; speedup vs baseline: 1.4436x; 1.0212x over previous
//
#include <hip/hip_runtime.h>

// Bahdanau attention fused kernel for MI355X (gfx950).
// scores[b][s] = softmax_s( v . tanh( hb[b,:] + enc[s,b,:] @ We ) )
// R19: B DECOUPLED FROM LDS. B-frags reg-loaded from fragment-contiguous wt2
//      (1KB/instr from L2, 1-step reg double-buffer, no barriers/no LDS for B).
//      Only A staged via LDS (f32 coalesced -> cvt -> pitch-80 tile, <=2-way
//      banks). ONE barrier + ONE counted WAITV(8) per step. 2 blocks/CU.

typedef _Float16 f16;
typedef _Float16 half4 __attribute__((ext_vector_type(4)));
typedef _Float16 half8 __attribute__((ext_vector_type(8)));
typedef float f32x4 __attribute__((ext_vector_type(4)));

#define KDIM 1024
#define SEQ  2048
#define MROWS 65536

// ---------------------------------------------------------------------------
// prep_w: enc-half of attn_w -> fragment-contiguous f16 tiles (validated R5/R16).
// Entry t = (ks*64 + g)*64 + l: wt2[t*8+j] = W[1024+ks*32+(l>>4)*8+j][g*16+(l&15)]
// B-frag (ks,g) for lane l = 16B at wt2 + t*16 bytes -> 1KB contiguous per wave.
// ---------------------------------------------------------------------------
__global__ __launch_bounds__(256) void prep_w(const float* __restrict__ w,
                                              f16* __restrict__ wt2) {
    int t  = blockIdx.x * 256 + threadIdx.x;   // 0..131071
    int l  = t & 63;
    int gk = t >> 6;
    int g  = gk & 63;
    int ks = gk >> 6;
    int kb = 1024 + ks * 32 + (l >> 4) * 8;
    int n  = g * 16 + (l & 15);
    half8 h;
#pragma unroll
    for (int j = 0; j < 8; ++j)
        h[j] = (f16)w[(size_t)(kb + j) * 1024 + n];
    *(half8*)&wt2[(size_t)t * 8] = h;
}

// ---------------------------------------------------------------------------
// prep_hb: hb[b][n] = attn_b[n] + sum_k hidden[b][k] * attn_w[k][n]  (f32)
// ---------------------------------------------------------------------------
__global__ __launch_bounds__(256) void prep_hb(const float* __restrict__ hidden,
                                               const float* __restrict__ attn_w,
                                               const float* __restrict__ attn_b,
                                               float* __restrict__ hb) {
    int b = blockIdx.x >> 2;
    int n = (blockIdx.x & 3) * 256 + threadIdx.x;
    const float* h = hidden + (size_t)b * 1024;
    float acc = attn_b[n];
#pragma unroll 8
    for (int k = 0; k < 1024; ++k)
        acc += h[k] * attn_w[(size_t)k * 1024 + n];
    hb[(size_t)b * 1024 + n] = acc;
}

// ---------------------------------------------------------------------------
// fused_energy: block = 128 rows x 128 N-slice (nq of 8); K = 32 steps of 32.
// 4 waves (2M x 2N), wave tile 64x64, frags 4x4, 16 MFMA/step/wave.
// Steady FIFO: entering step t outstanding = [A(t+1):4, B(t):4] = 8.
// Step t: issue A(t+2)+B(t+1) (->16) | WAITV(8) retires A(t+1),B(t) |
// LGKM0 | BAR | cvt+write A(t+1) -> buf[(t+1)&1] | compute(t) from buf[t&1],
// bf[t&1] regs. LGKM0-before-BAR also completes own frag ds_reads (race-safe).
// ---------------------------------------------------------------------------
__global__ __launch_bounds__(256, 2)
void fused_energy(const float* __restrict__ enc, const f16* __restrict__ wt2,
                  const float* __restrict__ hb, const float* __restrict__ vvec,
                  float* __restrict__ partout) {
    __shared__ __align__(16) char AB[2][10240];  // A f16 tile, row pitch 80B
    __shared__ float red[2][128];

    const int tid  = threadIdx.x;
    const int lane = tid & 63;
    const int wv   = tid >> 6;          // 0..3
    const int wm   = wv >> 1;           // 0..1: 64-row group
    const int wn   = wv & 1;            // 0..1: 64-col group
    const int l15  = lane & 15;
    const int l4   = lane >> 4;

    // XCD mapping: all 8 nq-slices of a row-tile consecutive on one XCD
    const int bid   = blockIdx.x;       // 0..4095
    const int xcd   = bid & 7;
    const int c     = bid >> 3;         // 0..511
    const int mt    = xcd * 64 + (c >> 3);       // 0..511
    const int nq    = c & 7;                     // 0..7
    const int mrow0 = mt * 128;
    const int ncol0 = nq * 128;

    // A staging: thread t -> rows {(t>>3) + i*32}, granule t&7 (16B of f32)
    const float* aSrc = enc + (size_t)(mrow0 + (tid >> 3)) * KDIM + (tid & 7) * 4;
    const int awByte  = (tid >> 3) * 80 + (tid & 7) * 8;   // + i*2560

    // B frag col-group base for this wave
    const int gbase = nq * 8 + wn * 4;

    // A frag read offsets (pitch 80 -> <=2-way banks)
    int aOff[4];
#pragma unroll
    for (int mi = 0; mi < 4; ++mi) {
        int r = wm * 64 + mi * 16 + l15;
        aOff[mi] = r * 80 + l4 * 16;
    }

    const f32x4 zero = {0.f, 0.f, 0.f, 0.f};
    f32x4 acc[4][4];
#pragma unroll
    for (int mi = 0; mi < 4; ++mi)
#pragma unroll
        for (int nj = 0; nj < 4; ++nj) acc[mi][nj] = zero;

    f32x4 rA0[4], rA1[4];
    half8 bfE[4], bfO[4], af[4];

#define WAITV(N) asm volatile("s_waitcnt vmcnt(" #N ")" ::: "memory")
#define LGKM0    asm volatile("s_waitcnt lgkmcnt(0)" ::: "memory")
#define BAR      __builtin_amdgcn_s_barrier()

#define LOADA(W, R)                                                           \
    { _Pragma("unroll") for (int i = 0; i < 4; ++i)                           \
        R[i] = *(const f32x4*)(aSrc + (size_t)(i * 32) * KDIM + (W) * 32); }
#define LOADB(W, BF)                                                          \
    { _Pragma("unroll") for (int nj = 0; nj < 4; ++nj)                        \
        BF[nj] = *(const half8*)(wt2 +                                        \
            ((size_t)((W) * 64 + gbase + nj) * 64 + lane) * 8); }
#define CVWR(P, R)                                                            \
    { char* b_ = AB[P];                                                       \
      _Pragma("unroll") for (int i = 0; i < 4; ++i) {                         \
          half4 h_;                                                           \
          _Pragma("unroll") for (int j = 0; j < 4; ++j) h_[j] = (f16)R[i][j]; \
          *(half4*)(b_ + awByte + i * 2560) = h_;                             \
      } }
#define COMPUTE(P, BF)                                                        \
    { const char* s_ = AB[P];                                                 \
      _Pragma("unroll") for (int j = 0; j < 4; ++j)                           \
          af[j] = *(const half8*)(s_ + aOff[j]);                              \
      __builtin_amdgcn_s_setprio(1);                                          \
      _Pragma("unroll") for (int mi = 0; mi < 4; ++mi)                        \
          _Pragma("unroll") for (int nj = 0; nj < 4; ++nj)                    \
              acc[mi][nj] = __builtin_amdgcn_mfma_f32_16x16x32_f16(           \
                  af[mi], BF[nj], acc[mi][nj], 0, 0, 0);                      \
      __builtin_amdgcn_s_setprio(0); }

    // ---- prologue: A(0) staged+written; A(1), B(0) in flight (8 out) ----
    LOADA(0, rA0);
    WAITV(0);
    CVWR(0, rA0);
    LOADA(1, rA1);
    LOADB(0, bfE);

    // ---- steady: t = 0..29 in parity pairs ----
    for (int t = 0; t < 30; t += 2) {
        // even t: compute buf0/bfE; A(t+1) in rA1 -> buf1; A(t+2) -> rA0
        LOADA(t + 2, rA0); LOADB(t + 1, bfO);
        WAITV(8); LGKM0; BAR;
        CVWR(1, rA1);
        COMPUTE(0, bfE);
        // odd t+1: compute buf1/bfO; A(t+2) in rA0 -> buf0; A(t+3) -> rA1
        LOADA(t + 3, rA1); LOADB(t + 2, bfE);
        WAITV(8); LGKM0; BAR;
        CVWR(0, rA0);
        COMPUTE(1, bfO);
    }
    // ---- t = 30: no A(32); B(31) issued ----
    LOADB(31, bfO);
    WAITV(4); LGKM0; BAR;    // retire A(31)+B(30); B(31) stays in flight
    CVWR(1, rA1);
    COMPUTE(0, bfE);
    // ---- t = 31 ----
    WAITV(0); LGKM0; BAR;
    COMPUTE(1, bfO);

#undef LOADA
#undef LOADB
#undef CVWR
#undef COMPUTE

    // ---- epilogue: e = acc + hb -> tanh -> * v -> per-row partial ----
    float vv[4];
#pragma unroll
    for (int nj = 0; nj < 4; ++nj)
        vv[nj] = vvec[ncol0 + wn * 64 + nj * 16 + l15];
#pragma unroll
    for (int mi = 0; mi < 4; ++mi) {
#pragma unroll
        for (int rg = 0; rg < 4; ++rg) {
            int rl = wm * 64 + mi * 16 + l4 * 4 + rg;     // local row 0..127
            const float* hbrow = hb + (size_t)((mrow0 + rl) & 31) * 1024
                                 + ncol0 + wn * 64 + l15;
            float sum = 0.f;
#pragma unroll
            for (int nj = 0; nj < 4; ++nj) {
                float e  = acc[mi][nj][rg] + hbrow[nj * 16];
                float e2 = __expf(2.f * e);
                sum += (1.f - 2.f / (e2 + 1.f)) * vv[nj];  // tanh(e) * v
            }
            float p = sum;
            p += __shfl_xor(p, 1);
            p += __shfl_xor(p, 2);
            p += __shfl_xor(p, 4);
            p += __shfl_xor(p, 8);
            if (l15 == 0) red[wn][rl] = p;
        }
    }
    __syncthreads();
    if (tid < 128) {
        float s = red[0][tid] + red[1][tid];
        partout[(size_t)nq * MROWS + mrow0 + tid] = s;
    }
}

// ---------------------------------------------------------------------------
// softmax over S=2048 per batch row; sums the 8 N-slice partials first.
// ---------------------------------------------------------------------------
__global__ __launch_bounds__(256) void softmax_rows(const float* __restrict__ part,
                                                    float* __restrict__ out) {
    const int b = blockIdx.x;
    const int tid  = threadIdx.x;
    const int lane = tid & 63;
    const int wv   = tid >> 6;
    __shared__ float sred[4];
    __shared__ float ssum[4];
    float x[8];
    float mx = -3.4e38f;
#pragma unroll
    for (int j = 0; j < 8; ++j) {
        int flat = (tid + j * 256) * 32 + b;              // row = s*32 + b
        float v = 0.f;
#pragma unroll
        for (int q = 0; q < 8; ++q) v += part[(size_t)q * MROWS + flat];
        x[j] = v;
        mx = fmaxf(mx, v);
    }
#pragma unroll
    for (int o = 1; o < 64; o <<= 1) mx = fmaxf(mx, __shfl_xor(mx, o));
    if (lane == 0) sred[wv] = mx;
    __syncthreads();
    mx = fmaxf(fmaxf(sred[0], sred[1]), fmaxf(sred[2], sred[3]));
    float s = 0.f;
#pragma unroll
    for (int j = 0; j < 8; ++j) { x[j] = __expf(x[j] - mx); s += x[j]; }
#pragma unroll
    for (int o = 1; o < 64; o <<= 1) s += __shfl_xor(s, o);
    if (lane == 0) ssum[wv] = s;
    __syncthreads();
    s = ssum[0] + ssum[1] + ssum[2] + ssum[3];
    float inv = 1.f / s;
#pragma unroll
    for (int j = 0; j < 8; ++j) out[(size_t)b * SEQ + tid + j * 256] = x[j] * inv;
}

extern "C" void kernel_launch(void* const* d_in, const int* in_sizes, int n_in,
                              void* d_out, int out_size, void* d_ws, size_t ws_size,
                              hipStream_t stream) {
    const float* hidden = (const float*)d_in[0];   // [32][1024]
    const float* enc    = (const float*)d_in[1];   // [2048][32][1024]
    const float* attn_w = (const float*)d_in[2];   // [2048][1024]
    const float* attn_b = (const float*)d_in[3];   // [1024]
    const float* v      = (const float*)d_in[4];   // [1024]
    float* out = (float*)d_out;                    // [32][2048]

    f16*   wt2  = (f16*)d_ws;                              // 2 MB frag-tiled We
    float* hb   = (float*)((char*)d_ws + 2097152);         // 128 KB
    float* part = (float*)((char*)d_ws + 2097152 + 131072); // 2 MB (8 slices)

    prep_w<<<512, 256, 0, stream>>>(attn_w, wt2);
    prep_hb<<<128, 256, 0, stream>>>(hidden, attn_w, attn_b, hb);
    fused_energy<<<4096, 256, 0, stream>>>(enc, wt2, hb, v, part);
    softmax_rows<<<32, 256, 0, stream>>>(part, out);
}

// Round 20
// 273.224 us; speedup vs baseline: 1.4457x; 1.0014x over previous
//
#include <hip/hip_runtime.h>

// Bahdanau attention fused kernel for MI355X (gfx950).
// scores[b][s] = softmax_s( v . tanh( hb[b,:] + enc[s,b,:] @ We ) )
// FINAL (R8/R10 best-measured, 261.8 us): 4-phase counted-vmcnt schedule.
// BM=256,BN=256,BK=64; 8 waves 2Mx4N; B via global_load_lds (pre-swizzled wt),
// A reg-staged f32->f16 issue-early/convert-late; waits P2 vmcnt(8),
// P3 vmcnt(4) (>=2-phase windows, never 0 mid-loop); XCD-grouped N-slices.

typedef _Float16 f16;
typedef _Float16 half8 __attribute__((ext_vector_type(8)));
typedef float f32x4 __attribute__((ext_vector_type(4)));

#define KDIM 1024
#define SEQ  2048
#define MROWS 65536

typedef __attribute__((address_space(1))) void gvoid;
typedef __attribute__((address_space(3))) void svoid;

__device__ __forceinline__ void gload_lds16(const void* g, void* l) {
    __builtin_amdgcn_global_load_lds((const gvoid*)g, (svoid*)l, 16, 0, 0);
}

// ---------------------------------------------------------------------------
// prep_w: transpose + f16-convert enc-half of attn_w into subtile images.
// Subtile id tk = ((nq*16 + t)*2 + kk): [256 n][32 k] LDS image, 16B block
// p = nloc*4 + ((kblk + (nloc>>1)) & 3); payload k = 1024 + t*64 + kk*32 + kblk*8 + j.
// ---------------------------------------------------------------------------
__global__ __launch_bounds__(256) void prep_w(const float* __restrict__ w,
                                              f16* __restrict__ wt) {
    int idx  = blockIdx.x * 256 + threadIdx.x;   // 0..131071
    int kblk = idx & 3;
    int nloc = (idx >> 2) & 255;
    int tk   = idx >> 10;                        // 0..127
    int kk = tk & 1, tt = (tk >> 1) & 15, nq = tk >> 5;
    int n_g = nq * 256 + nloc;
    int kb  = 1024 + tt * 64 + kk * 32 + kblk * 8;
    half8 h;
#pragma unroll
    for (int j = 0; j < 8; ++j)
        h[j] = (f16)w[(size_t)(kb + j) * 1024 + n_g];
    int p = nloc * 4 + ((kblk + (nloc >> 1)) & 3);
    *(half8*)&wt[(size_t)tk * 8192 + p * 8] = h;
}

// ---------------------------------------------------------------------------
// prep_hb: hb[b][n] = attn_b[n] + sum_k hidden[b][k] * attn_w[k][n]  (f32)
// ---------------------------------------------------------------------------
__global__ __launch_bounds__(256) void prep_hb(const float* __restrict__ hidden,
                                               const float* __restrict__ attn_w,
                                               const float* __restrict__ attn_b,
                                               float* __restrict__ hb) {
    int b = blockIdx.x >> 2;
    int n = (blockIdx.x & 3) * 256 + threadIdx.x;
    const float* h = hidden + (size_t)b * 1024;
    float acc = attn_b[n];
#pragma unroll 8
    for (int k = 0; k < 1024; ++k)
        acc += h[k] * attn_w[(size_t)k * 1024 + n];
    hb[(size_t)b * 1024 + n] = acc;
}

// ---------------------------------------------------------------------------
// fused_energy: 256 rows x 256 N-slice per block; K = 16 tiles of BK=64.
// 8 waves 2Mx4N, wave tile 128x64, frags 8(M)x4(N), 64 MFMA / wave / K-tile
// in 4 phases of 16. Steady-state FIFO (12 ops/tile): P0 issues B(t+1)x4,
// P2 issues A(t+2,0)x4 after vmcnt(8), P3 issues A(t+2,1)x4 after vmcnt(4).
// ---------------------------------------------------------------------------
__global__ __launch_bounds__(512, 2)
void fused_energy(const float* __restrict__ enc, const f16* __restrict__ wt,
                  const float* __restrict__ hb, const float* __restrict__ vvec,
                  float* __restrict__ partout) {
    __shared__ f16 Bls[2][2][8192];   // [parity][kk] 16 KB subtiles
    __shared__ f16 Als[2][2][8192];
    __shared__ float red[4][256];

    const int tid  = threadIdx.x;
    const int lane = tid & 63;
    const int wv   = tid >> 6;          // 0..7
    const int wm   = wv >> 2;           // 0..1
    const int wn   = wv & 3;            // 0..3
    const int l15  = lane & 15;
    const int l4   = lane >> 4;

    // XCD-bijective mapping: xcd owns 32 consecutive row-tiles; same-row quads co-XCD
    const int bid   = blockIdx.x;       // 0..1023
    const int xcd   = bid & 7;
    const int chunk = bid >> 3;
    const int mt    = xcd * 32 + (chunk >> 2);
    const int nq    = chunk & 3;
    const int mrow0 = mt * 256;
    const int ncol0 = nq * 256;

    const char* wtNq = (const char*)wt + (size_t)nq * 16 * 2 * 16384;
    const int stOff  = wv * 2048 + lane * 16;

    // A reg staging: thread -> row arow, k-half akh (16 f32 per kk subtile)
    const int arow = tid >> 1;
    const int akh  = tid & 1;
    const float* aG = enc + (size_t)(mrow0 + arow) * KDIM + akh * 16;
    const int pw0 = arow * 4 + ((akh * 2     + (arow >> 1)) & 3);
    const int pw1 = arow * 4 + ((akh * 2 + 1 + (arow >> 1)) & 3);

    int aOffB[8], bOffB[4];
#pragma unroll
    for (int mi = 0; mi < 8; ++mi) {
        int r = wm * 128 + mi * 16 + l15;
        aOffB[mi] = (r * 4 + ((l4 + (r >> 1)) & 3)) * 16;
    }
#pragma unroll
    for (int nj = 0; nj < 4; ++nj) {
        int n = wn * 64 + nj * 16 + l15;
        bOffB[nj] = (n * 4 + ((l4 + (n >> 1)) & 3)) * 16;
    }

    const f32x4 zero = {0.f, 0.f, 0.f, 0.f};
    f32x4 acc[8][4];
#pragma unroll
    for (int mi = 0; mi < 8; ++mi)
#pragma unroll
        for (int nj = 0; nj < 4; ++nj) acc[mi][nj] = zero;

    f32x4 rA0[4], rA1[4];
    half8 bf[4], af[4];

#define WAITV(N) asm volatile("s_waitcnt vmcnt(" #N ")" ::: "memory")
#define LGKM0    asm volatile("s_waitcnt lgkmcnt(0)" ::: "memory")
#define BAR      __builtin_amdgcn_s_barrier()
#define PRIO1    __builtin_amdgcn_s_setprio(1)
#define PRIO0    __builtin_amdgcn_s_setprio(0)

#define STAGE_B(T, KK)                                                        \
    {                                                                         \
        const char* s_ = wtNq + (size_t)((T) * 2 + (KK)) * 16384 + stOff;     \
        char* d_ = (char*)Bls + (((T) & 1) * 32768) + (KK) * 16384 + stOff;   \
        gload_lds16(s_, d_);                                                  \
        gload_lds16(s_ + 1024, d_ + 1024);                                    \
    }
#define LOADA(T, KK, R)                                                       \
    {                                                                         \
        const float* p_ = aG + (T) * 64 + (KK) * 32;                          \
        R[0] = *(const f32x4*)(p_);      R[1] = *(const f32x4*)(p_ + 4);      \
        R[2] = *(const f32x4*)(p_ + 8);  R[3] = *(const f32x4*)(p_ + 12);     \
    }
#define CVTA(PB, KK, R)                                                       \
    {                                                                         \
        half8 h0_, h1_;                                                       \
        _Pragma("unroll") for (int j = 0; j < 4; ++j) {                       \
            h0_[j] = (f16)R[0][j]; h0_[4 + j] = (f16)R[1][j];                 \
            h1_[j] = (f16)R[2][j]; h1_[4 + j] = (f16)R[3][j];                 \
        }                                                                     \
        char* d_ = (char*)Als + (PB) * 32768 + (KK) * 16384;                  \
        *(half8*)(d_ + pw0 * 16) = h0_;                                       \
        *(half8*)(d_ + pw1 * 16) = h1_;                                       \
    }
#define READB(PC, KK)                                                         \
    _Pragma("unroll") for (int nj = 0; nj < 4; ++nj)                          \
        bf[nj] = *(const half8*)((char*)Bls + (PC) * 32768 + (KK) * 16384 + bOffB[nj]);
#define READA(PC, KK, MH)                                                     \
    _Pragma("unroll") for (int i = 0; i < 4; ++i)                             \
        af[i] = *(const half8*)((char*)Als + (PC) * 32768 + (KK) * 16384 + aOffB[(MH) * 4 + i]);
#define MFMA16(MH)                                                            \
    PRIO1;                                                                    \
    _Pragma("unroll") for (int i = 0; i < 4; ++i)                             \
        _Pragma("unroll") for (int nj = 0; nj < 4; ++nj)                      \
            acc[(MH) * 4 + i][nj] = __builtin_amdgcn_mfma_f32_16x16x32_f16(   \
                af[i], bf[nj], acc[(MH) * 4 + i][nj], 0, 0, 0);               \
    PRIO0;

    // ---- prologue: tile 0 staged + converted; A(1) regs in flight (8 ops) ----
    STAGE_B(0, 0); STAGE_B(0, 1);          // 4 ops
    LOADA(0, 0, rA0); LOADA(0, 1, rA1);    // +8 = 12
    WAITV(4);                // B(0)x4 + A(0,0)x4 retired
    CVTA(0, 0, rA0);
    WAITV(0);                // A(0,1) retired
    CVTA(0, 1, rA1);
    LOADA(1, 0, rA0); LOADA(1, 1, rA1);    // 8 in flight
    LGKM0; BAR;

    // ---- steady loop: t = 0..13 ----
    // FIFO at P2 wait: [A(t+1,0)x4, A(t+1,1)x4, B(t+1)x4] = 12 -> vmcnt(8)
    // FIFO at P3 wait: [A(t+1,1)x4, B(t+1)x4, A(t+2,0)x4] = 12 -> vmcnt(4)
    for (int t = 0; t < 14; ++t) {
        const int cur = t & 1, nxt = cur ^ 1;
        // P0 (kk0, mi 0-3): stage both B halves of t+1
        STAGE_B(t + 1, 0); STAGE_B(t + 1, 1);
        READB(cur, 0); READA(cur, 0, 0);
        MFMA16(0);
        BAR;
        // P1 (kk0, mi 4-7)
        READA(cur, 0, 1);
        MFMA16(1);
        BAR;
        // P2 (kk1, mi 0-3): A(t+1,0) regs ready 4 phases after issue
        WAITV(8);
        CVTA(nxt, 0, rA0);
        LOADA(t + 2, 0, rA0);
        READB(cur, 1); READA(cur, 1, 0);
        MFMA16(0);
        LGKM0; BAR;
        // P3 (kk1, mi 4-7): A(t+1,1) regs + B(t+1) LDS retired before barrier
        WAITV(4);
        CVTA(nxt, 1, rA1);
        LOADA(t + 2, 1, rA1);
        READA(cur, 1, 1);
        MFMA16(1);
        LGKM0; BAR;
    }
    // ---- t = 14 (no t+2 loads) ----
    {
        const int cur = 0, nxt = 1;
        STAGE_B(15, 0); STAGE_B(15, 1);
        READB(cur, 0); READA(cur, 0, 0);
        MFMA16(0);
        BAR;
        READA(cur, 0, 1);
        MFMA16(1);
        BAR;
        WAITV(8);                       // drains A(15,0)
        CVTA(nxt, 0, rA0);
        READB(cur, 1); READA(cur, 1, 0);
        MFMA16(0);
        LGKM0; BAR;
        WAITV(0);                       // drains A(15,1) + B(15)
        CVTA(nxt, 1, rA1);
        READA(cur, 1, 1);
        MFMA16(1);
        LGKM0; BAR;
    }
    // ---- t = 15 (pure compute, everything resident) ----
    {
        const int cur = 1;
        READB(cur, 0); READA(cur, 0, 0);
        MFMA16(0);
        READA(cur, 0, 1);
        MFMA16(1);
        READB(cur, 1); READA(cur, 1, 0);
        MFMA16(0);
        READA(cur, 1, 1);
        MFMA16(1);
    }

#undef STAGE_B
#undef LOADA
#undef CVTA
#undef READB
#undef READA
#undef MFMA16

    // ---- epilogue: e = acc + hb -> tanh -> * v, partial over this N slice ----
    float vv[4];
#pragma unroll
    for (int nj = 0; nj < 4; ++nj) vv[nj] = vvec[ncol0 + wn * 64 + nj * 16 + l15];
#pragma unroll
    for (int mi = 0; mi < 8; ++mi) {
#pragma unroll
        for (int rg = 0; rg < 4; ++rg) {
            int rl = wm * 128 + mi * 16 + l4 * 4 + rg;    // local row 0..255
            const float* hbrow = hb + (size_t)((mrow0 + rl) & 31) * 1024
                                 + ncol0 + wn * 64 + l15;
            float sum = 0.f;
#pragma unroll
            for (int nj = 0; nj < 4; ++nj) {
                float e  = acc[mi][nj][rg] + hbrow[nj * 16];
                float e2 = __expf(2.f * e);
                sum += (1.f - 2.f / (e2 + 1.f)) * vv[nj];  // tanh(e) * v
            }
            float p = sum;
            p += __shfl_xor(p, 1);
            p += __shfl_xor(p, 2);
            p += __shfl_xor(p, 4);
            p += __shfl_xor(p, 8);
            if (l15 == 0) red[wn][rl] = p;
        }
    }
    __syncthreads();
    if (tid < 256) {
        float s = red[0][tid] + red[1][tid] + red[2][tid] + red[3][tid];
        partout[(size_t)nq * MROWS + mrow0 + tid] = s;
    }
}

// ---------------------------------------------------------------------------
// softmax over S=2048 per batch row; sums the 4 N-slice partials first.
// ---------------------------------------------------------------------------
__global__ __launch_bounds__(256) void softmax_rows(const float* __restrict__ part,
                                                    float* __restrict__ out) {
    const int b = blockIdx.x;
    const int tid  = threadIdx.x;
    const int lane = tid & 63;
    const int wv   = tid >> 6;
    __shared__ float sred[4];
    __shared__ float ssum[4];
    float x[8];
    float mx = -3.4e38f;
#pragma unroll
    for (int j = 0; j < 8; ++j) {
        int flat = (tid + j * 256) * 32 + b;              // row = s*32 + b
        float v = part[flat] + part[MROWS + flat]
                + part[2 * MROWS + flat] + part[3 * MROWS + flat];
        x[j] = v;
        mx = fmaxf(mx, v);
    }
#pragma unroll
    for (int o = 1; o < 64; o <<= 1) mx = fmaxf(mx, __shfl_xor(mx, o));
    if (lane == 0) sred[wv] = mx;
    __syncthreads();
    mx = fmaxf(fmaxf(sred[0], sred[1]), fmaxf(sred[2], sred[3]));
    float s = 0.f;
#pragma unroll
    for (int j = 0; j < 8; ++j) { x[j] = __expf(x[j] - mx); s += x[j]; }
#pragma unroll
    for (int o = 1; o < 64; o <<= 1) s += __shfl_xor(s, o);
    if (lane == 0) ssum[wv] = s;
    __syncthreads();
    s = ssum[0] + ssum[1] + ssum[2] + ssum[3];
    float inv = 1.f / s;
#pragma unroll
    for (int j = 0; j < 8; ++j) out[(size_t)b * SEQ + tid + j * 256] = x[j] * inv;
}

extern "C" void kernel_launch(void* const* d_in, const int* in_sizes, int n_in,
                              void* d_out, int out_size, void* d_ws, size_t ws_size,
                              hipStream_t stream) {
    const float* hidden = (const float*)d_in[0];   // [32][1024]
    const float* enc    = (const float*)d_in[1];   // [2048][32][1024]
    const float* attn_w = (const float*)d_in[2];   // [2048][1024]
    const float* attn_b = (const float*)d_in[3];   // [1024]
    const float* v      = (const float*)d_in[4];   // [1024]
    float* out = (float*)d_out;                    // [32][2048]

    f16*   wt   = (f16*)d_ws;                            // 2 MB tiled We
    float* hb   = (float*)((char*)d_ws + 2097152);       // 128 KB
    float* part = (float*)((char*)d_ws + 2097152 + 131072); // 1 MB N-partials

    prep_w<<<512, 256, 0, stream>>>(attn_w, wt);
    prep_hb<<<128, 256, 0, stream>>>(hidden, attn_w, attn_b, hb);
    fused_energy<<<1024, 512, 0, stream>>>(enc, wt, hb, v, part);
    softmax_rows<<<32, 256, 0, stream>>>(part, out);
}